// Round 14
// baseline (167.131 us; speedup 1.0000x reference)
//
#include <hip/hip_runtime.h>
#include <hip/hip_bf16.h>

#define NUM_TABLES 21
#define NUM_CATS   1000
#define EMB_DIM    16
#define CONCAT_DIM 344
#define OUT_DIM    32
#define NEG_SLOPE  0.01f

#define ROWS_PER_BLOCK 32          // 256 threads, 8 lanes per row (R7 layout)
#define CATS_PER_BLOCK (ROWS_PER_BLOCK * NUM_TABLES)  // 672 ints

typedef float f32x4 __attribute__((ext_vector_type(4)));
typedef unsigned int u32x2 __attribute__((ext_vector_type(2)));

// ---------- helpers ----------
__device__ __forceinline__ unsigned short f32_to_bf16_rne(float f) {
    unsigned int u = __float_as_uint(f);
    unsigned int r = u + 0x7FFFu + ((u >> 16) & 1u);  // round to nearest even
    return (unsigned short)(r >> 16);
}
__device__ __forceinline__ float lrelu(float v) {
    return v >= 0.f ? v : NEG_SLOPE * v;
}

// ---------- kernel 1: precompute P[t][c][j] = tables[t,c,:] . W[j, 16t:16t+16] (bf16)
// also packs wt[k][j] = W[j][336+k] (f32) for coalesced loads in kernel 2.
__global__ void build_P(const float* __restrict__ tables,
                        const float* __restrict__ W,
                        unsigned short* __restrict__ P,
                        float* __restrict__ wt) {
    int idx = blockIdx.x * 256 + threadIdx.x;
    if (idx < NUM_TABLES * NUM_CATS * OUT_DIM) {
        int j = idx & 31;
        int c = (idx >> 5) % NUM_CATS;
        int t = idx / (NUM_CATS * OUT_DIM);
        const float* trow = tables + (size_t)(t * NUM_CATS + c) * EMB_DIM;
        const float* wrow = W + (size_t)j * CONCAT_DIM + t * EMB_DIM;
        float acc = 0.f;
        #pragma unroll
        for (int k = 0; k < EMB_DIM; ++k) acc = fmaf(trow[k], wrow[k], acc);
        P[idx] = f32_to_bf16_rne(acc);
    }
    if (blockIdx.x == 0 && threadIdx.x < 8 * OUT_DIM) {
        int k = threadIdx.x >> 5;
        int j = threadIdx.x & 31;
        wt[k * OUT_DIM + j] = W[(size_t)j * CONCAT_DIM + (CONCAT_DIM - 8) + k];
    }
}

// ---------- kernel 2 (R7 layout; single change: NT loads on P gathers) ----------
// 8 lanes per row; each lane owns 4 consecutive outputs (8B gather per table).
// P gathers are nontemporal (L1 no-allocate): P thrashes L1 anyway (1.34 MB vs
// 32 KB, random); bypassing the L1 fill path should deepen miss-level
// parallelism if the TCP line-fill trackers are the current cap.
__global__ void __launch_bounds__(256)
fwd(const int* __restrict__ xcat,
    const float* __restrict__ xcont,
    const unsigned short* __restrict__ P,
    const float* __restrict__ Wc,
    const float* __restrict__ bc,
    const float* __restrict__ bias,
    const float* __restrict__ wt,
    float* __restrict__ out,
    int nrows) {
    __shared__ int s_cats[CATS_PER_BLOCK];

    const int tid = threadIdx.x;
    const long blk_cat_base = (long)blockIdx.x * CATS_PER_BLOCK;
    const long total_cats = (long)nrows * NUM_TABLES;

    // coalesced stage of this block's 32 rows of categorical indices
    #pragma unroll
    for (int i = 0; i < 3; ++i) {
        int li = tid + i * 256;
        if (li < CATS_PER_BLOCK) {
            long g = blk_cat_base + li;
            if (g < total_cats) s_cats[li] = xcat[g];
        }
    }
    __syncthreads();

    const int row_local = tid >> 3;
    const int l = tid & 7;
    const int row = blockIdx.x * ROWS_PER_BLOCK + row_local;
    if (row >= nrows) return;

    // offsets (LDS broadcast reads)
    int offs[NUM_TABLES];
    #pragma unroll
    for (int t = 0; t < NUM_TABLES; ++t) {
        int c = s_cats[row_local * NUM_TABLES + t];
        offs[t] = (t * NUM_CATS + c) * OUT_DIM + l * 4;
    }

    // gathers: nontemporal 8B loads (2 dwords = 4 bf16)
    u32x2 u[NUM_TABLES];
    #pragma unroll
    for (int t = 0; t < NUM_TABLES; ++t)
        u[t] = __builtin_nontemporal_load(reinterpret_cast<const u32x2*>(P + offs[t]));

    // accumulate: unpack bf16 pair from each dword via shift/mask
    float acc[4];
    const float* bsrc = bias + l * 4;
    #pragma unroll
    for (int m = 0; m < 4; ++m) acc[m] = bsrc[m];

    #pragma unroll
    for (int t = 0; t < NUM_TABLES; ++t) {
        unsigned int w0 = u[t].x, w1 = u[t].y;
        acc[0] += __uint_as_float(w0 << 16);
        acc[1] += __uint_as_float(w0 & 0xFFFF0000u);
        acc[2] += __uint_as_float(w1 << 16);
        acc[3] += __uint_as_float(w1 & 0xFFFF0000u);
    }

    // continuous branch
    float x = xcont[row];
    #pragma unroll
    for (int k = 0; k < 8; ++k) {
        float cv = lrelu(fmaf(x, Wc[k], bc[k]));
        const float* w = wt + k * OUT_DIM + l * 4;
        #pragma unroll
        for (int m = 0; m < 4; ++m)
            acc[m] = fmaf(cv, w[m], acc[m]);
    }

    #pragma unroll
    for (int m = 0; m < 4; ++m) acc[m] = lrelu(acc[m]);

    f32x4 v = { acc[0], acc[1], acc[2], acc[3] };
    *reinterpret_cast<f32x4*>(out + (size_t)row * OUT_DIM + l * 4) = v;
}

extern "C" void kernel_launch(void* const* d_in, const int* in_sizes, int n_in,
                              void* d_out, int out_size, void* d_ws, size_t ws_size,
                              hipStream_t stream) {
    const int*   xcat   = (const int*)d_in[0];
    const float* xcont  = (const float*)d_in[1];
    const float* tables = (const float*)d_in[2];
    const float* Wc     = (const float*)d_in[3];
    const float* bc     = (const float*)d_in[4];
    const float* W      = (const float*)d_in[5];
    const float* bias   = (const float*)d_in[6];
    float* out = (float*)d_out;

    int nrows = in_sizes[0] / NUM_TABLES;

    const size_t P_elems = (size_t)NUM_TABLES * NUM_CATS * OUT_DIM;  // 672000
    const size_t P_bytes = P_elems * sizeof(unsigned short);
    const size_t wt_off  = P_bytes;

    unsigned short* P = (unsigned short*)d_ws;
    float* wt = (float*)((char*)d_ws + wt_off);

    int blocks1 = (int)((P_elems + 255) / 256);
    build_P<<<blocks1, 256, 0, stream>>>(tables, W, P, wt);

    int blocks2 = (nrows + ROWS_PER_BLOCK - 1) / ROWS_PER_BLOCK;
    fwd<<<blocks2, 256, 0, stream>>>(xcat, xcont, P, Wc, bc, bias, wt, out, nrows);
}

// Round 15
// 91.052 us; speedup vs baseline: 1.8356x; 1.8356x over previous
//
#include <hip/hip_runtime.h>
#include <hip/hip_bf16.h>

#define NUM_TABLES 21
#define NUM_CATS   1000
#define EMB_DIM    16
#define CONCAT_DIM 344
#define OUT_DIM    32
#define NEG_SLOPE  0.01f

#define ROWS_PER_BLOCK 32          // 256 threads, 8 lanes per row (R7 layout)
#define CATS_PER_BLOCK (ROWS_PER_BLOCK * NUM_TABLES)  // 672 ints

typedef float f32x4 __attribute__((ext_vector_type(4)));

// ---------- helpers ----------
__device__ __forceinline__ unsigned short f32_to_bf16_rne(float f) {
    unsigned int u = __float_as_uint(f);
    unsigned int r = u + 0x7FFFu + ((u >> 16) & 1u);  // round to nearest even
    return (unsigned short)(r >> 16);
}
__device__ __forceinline__ float bf16_to_f32(unsigned short h) {
    return __uint_as_float(((unsigned int)h) << 16);
}
__device__ __forceinline__ float lrelu(float v) {
    return v >= 0.f ? v : NEG_SLOPE * v;
}

// ---------- kernel 1: precompute P[t][c][j] = tables[t,c,:] . W[j, 16t:16t+16] (bf16)
// also packs wt[k][j] = W[j][336+k] (f32) for coalesced loads in kernel 2.
__global__ void build_P(const float* __restrict__ tables,
                        const float* __restrict__ W,
                        unsigned short* __restrict__ P,
                        float* __restrict__ wt) {
    int idx = blockIdx.x * 256 + threadIdx.x;
    if (idx < NUM_TABLES * NUM_CATS * OUT_DIM) {
        int j = idx & 31;
        int c = (idx >> 5) % NUM_CATS;
        int t = idx / (NUM_CATS * OUT_DIM);
        const float* trow = tables + (size_t)(t * NUM_CATS + c) * EMB_DIM;
        const float* wrow = W + (size_t)j * CONCAT_DIM + t * EMB_DIM;
        float acc = 0.f;
        #pragma unroll
        for (int k = 0; k < EMB_DIM; ++k) acc = fmaf(trow[k], wrow[k], acc);
        P[idx] = f32_to_bf16_rne(acc);
    }
    if (blockIdx.x == 0 && threadIdx.x < 8 * OUT_DIM) {
        int k = threadIdx.x >> 5;
        int j = threadIdx.x & 31;
        wt[k * OUT_DIM + j] = W[(size_t)j * CONCAT_DIM + (CONCAT_DIM - 8) + k];
    }
}

// ---------- kernel 2 (R7 layout; single change vs R7: NT load on x_cat) ----------
// 8 lanes per row; each lane owns 4 consecutive outputs. x_cat is a read-once
// 42 MB stream — NT (no L2 allocate) keeps it from evicting the 1.34 MB P
// table out of L2, cutting the P-gather latency term. P gathers stay plain
// (L2-cached; R14 proved NT there is disastrous). Out store stays plain
// (R6 proved NT store breaks post-timing readback).
__global__ void __launch_bounds__(256)
fwd(const int* __restrict__ xcat,
    const float* __restrict__ xcont,
    const unsigned short* __restrict__ P,
    const float* __restrict__ Wc,
    const float* __restrict__ bc,
    const float* __restrict__ bias,
    const float* __restrict__ wt,
    float* __restrict__ out,
    int nrows) {
    __shared__ int s_cats[CATS_PER_BLOCK];

    const int tid = threadIdx.x;
    const long blk_cat_base = (long)blockIdx.x * CATS_PER_BLOCK;
    const long total_cats = (long)nrows * NUM_TABLES;

    // coalesced stage of this block's 32 rows of categorical indices (NT)
    #pragma unroll
    for (int i = 0; i < 3; ++i) {
        int li = tid + i * 256;
        if (li < CATS_PER_BLOCK) {
            long g = blk_cat_base + li;
            if (g < total_cats)
                s_cats[li] = __builtin_nontemporal_load(xcat + g);
        }
    }
    __syncthreads();

    const int row_local = tid >> 3;
    const int l = tid & 7;
    const int row = blockIdx.x * ROWS_PER_BLOCK + row_local;
    if (row >= nrows) return;

    // offsets (LDS broadcast reads)
    int offs[NUM_TABLES];
    #pragma unroll
    for (int t = 0; t < NUM_TABLES; ++t) {
        int c = s_cats[row_local * NUM_TABLES + t];
        offs[t] = (t * NUM_CATS + c) * OUT_DIM + l * 4;
    }

    // gathers: plain 8B loads (L2-served)
    ushort4 u[NUM_TABLES];
    #pragma unroll
    for (int t = 0; t < NUM_TABLES; ++t)
        u[t] = *reinterpret_cast<const ushort4*>(P + offs[t]);

    // accumulate
    float acc[4];
    const float* bsrc = bias + l * 4;
    #pragma unroll
    for (int m = 0; m < 4; ++m) acc[m] = bsrc[m];

    #pragma unroll
    for (int t = 0; t < NUM_TABLES; ++t) {
        acc[0] += bf16_to_f32(u[t].x);
        acc[1] += bf16_to_f32(u[t].y);
        acc[2] += bf16_to_f32(u[t].z);
        acc[3] += bf16_to_f32(u[t].w);
    }

    // continuous branch
    float x = xcont[row];
    #pragma unroll
    for (int k = 0; k < 8; ++k) {
        float cv = lrelu(fmaf(x, Wc[k], bc[k]));
        const float* w = wt + k * OUT_DIM + l * 4;
        #pragma unroll
        for (int m = 0; m < 4; ++m)
            acc[m] = fmaf(cv, w[m], acc[m]);
    }

    #pragma unroll
    for (int m = 0; m < 4; ++m) acc[m] = lrelu(acc[m]);

    f32x4 v = { acc[0], acc[1], acc[2], acc[3] };
    *reinterpret_cast<f32x4*>(out + (size_t)row * OUT_DIM + l * 4) = v;
}

extern "C" void kernel_launch(void* const* d_in, const int* in_sizes, int n_in,
                              void* d_out, int out_size, void* d_ws, size_t ws_size,
                              hipStream_t stream) {
    const int*   xcat   = (const int*)d_in[0];
    const float* xcont  = (const float*)d_in[1];
    const float* tables = (const float*)d_in[2];
    const float* Wc     = (const float*)d_in[3];
    const float* bc     = (const float*)d_in[4];
    const float* W      = (const float*)d_in[5];
    const float* bias   = (const float*)d_in[6];
    float* out = (float*)d_out;

    int nrows = in_sizes[0] / NUM_TABLES;

    const size_t P_elems = (size_t)NUM_TABLES * NUM_CATS * OUT_DIM;  // 672000
    const size_t P_bytes = P_elems * sizeof(unsigned short);
    const size_t wt_off  = P_bytes;

    unsigned short* P = (unsigned short*)d_ws;
    float* wt = (float*)((char*)d_ws + wt_off);

    int blocks1 = (int)((P_elems + 255) / 256);
    build_P<<<blocks1, 256, 0, stream>>>(tables, W, P, wt);

    int blocks2 = (nrows + ROWS_PER_BLOCK - 1) / ROWS_PER_BLOCK;
    fwd<<<blocks2, 256, 0, stream>>>(xcat, xcont, P, Wc, bc, bias, wt, out, nrows);
}

// Round 16
// 77.153 us; speedup vs baseline: 2.1662x; 1.1802x over previous
//
#include <hip/hip_runtime.h>
#include <hip/hip_bf16.h>

#define NUM_TABLES 21
#define NUM_CATS   1000
#define EMB_DIM    16
#define CONCAT_DIM 344
#define OUT_DIM    32
#define NEG_SLOPE  0.01f

#define ROWS_PER_BLOCK 32          // 256 threads, 8 lanes per row
#define CATS_PER_BLOCK (ROWS_PER_BLOCK * NUM_TABLES)  // 672 ints

typedef float f32x4 __attribute__((ext_vector_type(4)));

// ---------- helpers ----------
__device__ __forceinline__ unsigned short f32_to_bf16_rne(float f) {
    unsigned int u = __float_as_uint(f);
    unsigned int r = u + 0x7FFFu + ((u >> 16) & 1u);  // round to nearest even
    return (unsigned short)(r >> 16);
}
__device__ __forceinline__ float bf16_to_f32(unsigned short h) {
    return __uint_as_float(((unsigned int)h) << 16);
}
__device__ __forceinline__ float lrelu(float v) {
    return v >= 0.f ? v : NEG_SLOPE * v;
}

// ---------- kernel 1: precompute P[t][c][j] = tables[t,c,:] . W[j, 16t:16t+16] (bf16)
// One P row = 32 bf16 = 64 B = exactly one cache line per (table, category).
// Also packs wt[k][j] = W[j][336+k] (f32) for coalesced loads in kernel 2.
__global__ void build_P(const float* __restrict__ tables,
                        const float* __restrict__ W,
                        unsigned short* __restrict__ P,
                        float* __restrict__ wt) {
    int idx = blockIdx.x * 256 + threadIdx.x;
    if (idx < NUM_TABLES * NUM_CATS * OUT_DIM) {
        int j = idx & 31;
        int c = (idx >> 5) % NUM_CATS;
        int t = idx / (NUM_CATS * OUT_DIM);
        const float* trow = tables + (size_t)(t * NUM_CATS + c) * EMB_DIM;
        const float* wrow = W + (size_t)j * CONCAT_DIM + t * EMB_DIM;
        float acc = 0.f;
        #pragma unroll
        for (int k = 0; k < EMB_DIM; ++k) acc = fmaf(trow[k], wrow[k], acc);
        P[idx] = f32_to_bf16_rne(acc);
    }
    if (blockIdx.x == 0 && threadIdx.x < 8 * OUT_DIM) {
        int k = threadIdx.x >> 5;
        int j = threadIdx.x & 31;
        wt[k * OUT_DIM + j] = W[(size_t)j * CONCAT_DIM + (CONCAT_DIM - 8) + k];
    }
}

// ---------- kernel 2 (final: R7 structure, plain loads everywhere) ----------
// 8 lanes per row; each lane owns 4 consecutive outputs. x_cat staged through
// LDS (coalesced). The 21 P gathers are the kernel: 10.5M independent random
// 64B line-misses served by L2 at the TCP miss-service equilibrium
// (~4.6 cyc/miss/CU) — the measured structural floor for this op.
// No NT hints: NT-load on P bypasses L2 (R14: 2.2x worse); NT-store on out
// breaks post-timing readback (R6).
__global__ void __launch_bounds__(256)
fwd(const int* __restrict__ xcat,
    const float* __restrict__ xcont,
    const unsigned short* __restrict__ P,
    const float* __restrict__ Wc,
    const float* __restrict__ bc,
    const float* __restrict__ bias,
    const float* __restrict__ wt,
    float* __restrict__ out,
    int nrows) {
    __shared__ int s_cats[CATS_PER_BLOCK];

    const int tid = threadIdx.x;
    const long blk_cat_base = (long)blockIdx.x * CATS_PER_BLOCK;
    const long total_cats = (long)nrows * NUM_TABLES;

    // coalesced stage of this block's 32 rows of categorical indices
    #pragma unroll
    for (int i = 0; i < 3; ++i) {
        int li = tid + i * 256;
        if (li < CATS_PER_BLOCK) {
            long g = blk_cat_base + li;
            if (g < total_cats) s_cats[li] = xcat[g];
        }
    }
    __syncthreads();

    const int row_local = tid >> 3;
    const int l = tid & 7;
    const int row = blockIdx.x * ROWS_PER_BLOCK + row_local;
    if (row >= nrows) return;

    // offsets (LDS broadcast reads)
    int offs[NUM_TABLES];
    #pragma unroll
    for (int t = 0; t < NUM_TABLES; ++t) {
        int c = s_cats[row_local * NUM_TABLES + t];
        offs[t] = (t * NUM_CATS + c) * OUT_DIM + l * 4;
    }

    // gathers: plain 8B loads (L2-served)
    ushort4 u[NUM_TABLES];
    #pragma unroll
    for (int t = 0; t < NUM_TABLES; ++t)
        u[t] = *reinterpret_cast<const ushort4*>(P + offs[t]);

    // accumulate
    float acc[4];
    const float* bsrc = bias + l * 4;
    #pragma unroll
    for (int m = 0; m < 4; ++m) acc[m] = bsrc[m];

    #pragma unroll
    for (int t = 0; t < NUM_TABLES; ++t) {
        acc[0] += bf16_to_f32(u[t].x);
        acc[1] += bf16_to_f32(u[t].y);
        acc[2] += bf16_to_f32(u[t].z);
        acc[3] += bf16_to_f32(u[t].w);
    }

    // continuous branch
    float x = xcont[row];
    #pragma unroll
    for (int k = 0; k < 8; ++k) {
        float cv = lrelu(fmaf(x, Wc[k], bc[k]));
        const float* w = wt + k * OUT_DIM + l * 4;
        #pragma unroll
        for (int m = 0; m < 4; ++m)
            acc[m] = fmaf(cv, w[m], acc[m]);
    }

    #pragma unroll
    for (int m = 0; m < 4; ++m) acc[m] = lrelu(acc[m]);

    f32x4 v = { acc[0], acc[1], acc[2], acc[3] };
    *reinterpret_cast<f32x4*>(out + (size_t)row * OUT_DIM + l * 4) = v;
}

extern "C" void kernel_launch(void* const* d_in, const int* in_sizes, int n_in,
                              void* d_out, int out_size, void* d_ws, size_t ws_size,
                              hipStream_t stream) {
    const int*   xcat   = (const int*)d_in[0];
    const float* xcont  = (const float*)d_in[1];
    const float* tables = (const float*)d_in[2];
    const float* Wc     = (const float*)d_in[3];
    const float* bc     = (const float*)d_in[4];
    const float* W      = (const float*)d_in[5];
    const float* bias   = (const float*)d_in[6];
    float* out = (float*)d_out;

    int nrows = in_sizes[0] / NUM_TABLES;

    const size_t P_elems = (size_t)NUM_TABLES * NUM_CATS * OUT_DIM;  // 672000
    const size_t P_bytes = P_elems * sizeof(unsigned short);
    const size_t wt_off  = P_bytes;

    unsigned short* P = (unsigned short*)d_ws;
    float* wt = (float*)((char*)d_ws + wt_off);

    int blocks1 = (int)((P_elems + 255) / 256);
    build_P<<<blocks1, 256, 0, stream>>>(tables, W, P, wt);

    int blocks2 = (nrows + ROWS_PER_BLOCK - 1) / ROWS_PER_BLOCK;
    fwd<<<blocks2, 256, 0, stream>>>(xcat, xcont, P, Wc, bc, bias, wt, out, nrows);
}